// Round 14
// baseline (84.297 us; speedup 1.0000x reference)
//
#include <hip/hip_runtime.h>

// INP=4096 MSK=64 HID=64 OUT=10  L1=64 L2=256 L3=128  B=16384  WVEC=4810
// k_prep : W1 LDS-tiled transpose -> f16; W2/W3 f16; W4 fragment-order f16.
// k_main : grid 256 x 512. TWO-STAGE GATHER PIPELINE:
//   wave 6 issues H0 (samples 0-31) gathers at B0; wave 7 issues H1 at B1
//   (delayed -> H0 queue priority). Front (waves 0-5) covers H0; H0 drains
//   at B4a; H0's inp-GEMM (waves 0-6) covers H1 while wave 7 drains it;
//   H1 inp-GEMM on 8 waves; out-phase 4+4 waves by half. Raw barriers keep
//   gather loads outstanding across phases.

typedef _Float16 f16;
typedef _Float16 f16x8 __attribute__((ext_vector_type(8)));
typedef _Float16 f16x4 __attribute__((ext_vector_type(4)));
typedef float    f32x4 __attribute__((ext_vector_type(4)));

#define NPAD 4864   // 4810 W4 rows padded to 76*64

#define BAR() do { asm volatile("s_waitcnt lgkmcnt(0)" ::: "memory"); \
                   __builtin_amdgcn_s_barrier();                      \
                   asm volatile("" ::: "memory"); } while (0)

// ---------------------------------------------------------------- prep
__global__ __launch_bounds__(256) void k_prep(
    const float* __restrict__ W1, const float* __restrict__ W2,
    const float* __restrict__ W3, const float* __restrict__ W4,
    f16* __restrict__ W1Th, f16* __restrict__ W2h,
    f16* __restrict__ W3h, f16* __restrict__ W4s)
{
    const int bid = blockIdx.x;
    const int t = threadIdx.x;

    if (bid < 64) {
        // ---- W1[64][4096] -> W1Th[4096][64], LDS-tiled 64x64 transpose
        __shared__ float tile[64][65];
        const int r4 = t >> 6, c0 = t & 63;
        #pragma unroll
        for (int rr = 0; rr < 16; ++rr) {
            const int i = rr * 4 + r4;
            tile[i][c0] = W1[(size_t)i * 4096 + bid * 64 + c0];
        }
        __syncthreads();
        #pragma unroll
        for (int rr = 0; rr < 16; ++rr) {
            const int jj = rr * 4 + r4;
            W1Th[(size_t)(bid * 64 + jj) * 64 + c0] = (f16)tile[c0][jj];
        }
        return;
    }

    const int tid = (bid - 64) * 256 + t;
    const int stride = (gridDim.x - 64) * 256;
    for (int e = tid; e < NPAD * 128; e += stride) {
        const int j    = e & 7;
        const int lane = (e >> 3) & 63;
        const int mt   = (e >> 9) & 3;
        const int kk   = (e >> 11) & 3;
        const int c    = e >> 13;
        const int lr = lane & 15, g = lane >> 4;
        const int row = 64 * c + 16 * mt + lr;
        const int col = 32 * kk + 8 * g + j;
        W4s[e] = (row < 4810) ? (f16)W4[(size_t)row * 128 + col] : (f16)0.f;
    }
    for (int e = tid; e < 256 * 64; e += stride)  W2h[e] = (f16)W2[e];
    for (int e = tid; e < 128 * 256; e += stride) W3h[e] = (f16)W3[e];
}

// ---------------------------------------------------------------- main
__global__ __launch_bounds__(512, 2) void k_main(
    const float* __restrict__ data, const int* __restrict__ midx,
    const f16* __restrict__ W1Th, const float* __restrict__ b1,
    const f16* __restrict__ W2h, const float* __restrict__ b2,
    const f16* __restrict__ W3h, const float* __restrict__ b3,
    const f16* __restrict__ W4s, const float* __restrict__ b4,
    float* __restrict__ out)
{
    __shared__ __align__(16) int   idx_s[64 * 64];    // 16 KB
    __shared__ __align__(16) char  h1b[8192];
    __shared__ __align__(16) char  h2b[32768];
    __shared__ __align__(16) char  h3b[16384];
    __shared__ __align__(16) float xm_s[64 * 68];
    __shared__ __align__(16) float hid_s[64 * 68];
    __shared__ __align__(16) f16   w64_s[64 * 64];
    __shared__ __align__(16) float res_s[64 * 12];
    __shared__ __align__(16) float res_b[64 * 12];

    const int t = threadIdx.x, w = t >> 6, lane = t & 63;
    const int lr = lane & 15, g = lane >> 4;
    const int row0 = blockIdx.x * 64;
    const f32x4 zero = {0.f, 0.f, 0.f, 0.f};

    // ---- stage idx (all waves)
    for (int e = t; e < 4096; e += 512)
        idx_s[e] = midx[(size_t)row0 * 64 + e];
    BAR();                                   // B0: idx ready

    float xr[32];                            // live on gather waves 6,7

    // ---- [gather H0 issue | L1 dedup on waves 0-5]; wave 7 parks
    if (w == 6) {
        #pragma unroll
        for (int k = 0; k < 32; ++k)
            xr[k] = data[(size_t)(row0 + k) * 4096 + idx_s[k * 64 + lane]];
        __builtin_amdgcn_sched_barrier(0);
    } else if (w < 6) {
        const f32x4 b1v = *(const f32x4*)&b1[lr * 4];
        for (int sp = w; sp < 32; sp += 6) {
            const int s0 = 2 * sp, s1 = s0 + 1;
            f32x4 a0 = zero, a1 = zero;
            #pragma unroll
            for (int tt = 0; tt < 16; ++tt) {
                const int i = g * 16 + tt;
                const int c0 = idx_s[s0 * 64 + i];
                const int q0 = (i > 0) ? idx_s[s0 * 64 + i - 1] : -1;
                const int c1 = idx_s[s1 * 64 + i];
                const int q1 = (i > 0) ? idx_s[s1 * 64 + i - 1] : -1;
                const f16x4 w0 = *(const f16x4*)&W1Th[c0 * 64 + lr * 4];
                const f16x4 w1 = *(const f16x4*)&W1Th[c1 * 64 + lr * 4];
                #pragma unroll
                for (int q = 0; q < 4; ++q) {
                    a0[q] += (c0 != q0) ? (float)w0[q] : 0.f;
                    a1[q] += (c1 != q1) ? (float)w1[q] : 0.f;
                }
            }
            #pragma unroll
            for (int q = 0; q < 4; ++q) {
                a0[q] += __shfl_xor(a0[q], 16);
                a0[q] += __shfl_xor(a0[q], 32);
                a1[q] += __shfl_xor(a1[q], 16);
                a1[q] += __shfl_xor(a1[q], 32);
            }
            if (g == 0) {
                f16x4 h0, h1v;
                #pragma unroll
                for (int q = 0; q < 4; ++q) {
                    h0[q]  = (f16)fmaxf(a0[q] + b1v[q], 0.f);
                    h1v[q] = (f16)fmaxf(a1[q] + b1v[q], 0.f);
                }
                *(f16x4*)(h1b + ((s0 * 128 + lr * 8) ^ ((s0 & 7) << 4))) = h0;
                *(f16x4*)(h1b + ((s1 * 128 + lr * 8) ^ ((s1 & 7) << 4))) = h1v;
            }
        }
    }
    BAR();                                   // B1: h1 ready

    // ---- [gather H1 issue | L2 layer on waves 0-5]; wave 6 parks
    if (w == 7) {
        #pragma unroll
        for (int k = 0; k < 32; ++k)
            xr[k] = data[(size_t)(row0 + 32 + k) * 4096 + idx_s[(32 + k) * 64 + lane]];
        __builtin_amdgcn_sched_barrier(0);
    } else if (w < 6) {
        f16x8 bh[4][2];
        #pragma unroll
        for (int rt = 0; rt < 4; ++rt)
            #pragma unroll
            for (int kk = 0; kk < 2; ++kk) {
                const int s = 16 * rt + lr;
                bh[rt][kk] = *(const f16x8*)(h1b + ((s * 128 + (32 * kk + 8 * g) * 2) ^ ((s & 7) << 4)));
            }
        for (int nb = w; nb < 8; nb += 6) {
            const int n0 = 32 * nb;
            f16x8 a2[2][2];
            #pragma unroll
            for (int mt = 0; mt < 2; ++mt)
                #pragma unroll
                for (int kk = 0; kk < 2; ++kk)
                    a2[mt][kk] = *(const f16x8*)&W2h[(n0 + 16 * mt + lr) * 64 + 32 * kk + 8 * g];
            f32x4 acc2[2][4];
            #pragma unroll
            for (int mt = 0; mt < 2; ++mt)
                #pragma unroll
                for (int rt = 0; rt < 4; ++rt) {
                    acc2[mt][rt] = __builtin_amdgcn_mfma_f32_16x16x32_f16(a2[mt][0], bh[rt][0], zero, 0, 0, 0);
                    acc2[mt][rt] = __builtin_amdgcn_mfma_f32_16x16x32_f16(a2[mt][1], bh[rt][1], acc2[mt][rt], 0, 0, 0);
                }
            #pragma unroll
            for (int mt = 0; mt < 2; ++mt) {
                const f32x4 bv = *(const f32x4*)&b2[n0 + 16 * mt + 4 * g];
                #pragma unroll
                for (int rt = 0; rt < 4; ++rt) {
                    const int s = 16 * rt + lr;
                    f16x4 hv;
                    #pragma unroll
                    for (int q = 0; q < 4; ++q)
                        hv[q] = (f16)fmaxf(acc2[mt][rt][q] + bv[q], 0.f);
                    *(f16x4*)(h2b + ((s * 512 + (n0 + 16 * mt + 4 * g) * 2) ^ ((s & 7) << 4))) = hv;
                }
            }
        }
    }
    BAR();                                   // B2: h2 ready

    if (w < 6) {                             // ---- L3 layer on waves 0-5
        for (int nb = w; nb < 8; nb += 6) {
            const int n0 = 16 * nb;
            f32x4 acc3[4] = {zero, zero, zero, zero};
            #pragma unroll 2
            for (int kk = 0; kk < 8; ++kk) {
                const f16x8 a3 = *(const f16x8*)&W3h[(n0 + lr) * 256 + 32 * kk + 8 * g];
                #pragma unroll
                for (int rt = 0; rt < 4; ++rt) {
                    const int s = 16 * rt + lr;
                    const f16x8 bb = *(const f16x8*)(h2b + ((s * 512 + (32 * kk + 8 * g) * 2) ^ ((s & 7) << 4)));
                    acc3[rt] = __builtin_amdgcn_mfma_f32_16x16x32_f16(a3, bb, acc3[rt], 0, 0, 0);
                }
            }
            const f32x4 bv3 = *(const f32x4*)&b3[n0 + 4 * g];
            #pragma unroll
            for (int rt = 0; rt < 4; ++rt) {
                const int s = 16 * rt + lr;
                f16x4 hv;
                #pragma unroll
                for (int q = 0; q < 4; ++q)
                    hv[q] = (f16)fmaxf(acc3[rt][q] + bv3[q], 0.f);
                *(f16x4*)(h3b + ((s * 256 + (n0 + 4 * g) * 2) ^ ((s & 7) << 4))) = hv;
            }
        }
    }
    BAR();                                   // B3: h3 ready

    if (w == 6) {                            // ---- drain H0 -> xm_s[0..31]
        #pragma unroll
        for (int k = 0; k < 32; ++k)
            xm_s[k * 68 + lane] = xr[k];
    }
    BAR();                                   // B4a: xm_H0 ready

    const char* W4b = (const char*)W4s;
    const int afoff = lane * 16;

    // chunk GEMM: acc[mt][u2] over 2 u-sets of one sample-half
    auto gemm_chunk = [&](int c, const f16x8 bf[4][2], f32x4 acc[4][2]) {
        #pragma unroll
        for (int mt = 0; mt < 4; ++mt)
            #pragma unroll
            for (int u2 = 0; u2 < 2; ++u2) acc[mt][u2] = zero;
        #pragma unroll
        for (int kk = 0; kk < 4; ++kk) {
            f16x8 af[4];
            const char* cb_ = W4b + (size_t)c * 16384 + kk * 4096 + afoff;
            af[0] = *(const f16x8*)(cb_);
            af[1] = *(const f16x8*)(cb_ + 1024);
            af[2] = *(const f16x8*)(cb_ + 2048);
            af[3] = *(const f16x8*)(cb_ + 3072);
            #pragma unroll
            for (int mt = 0; mt < 4; ++mt)
                #pragma unroll
                for (int u2 = 0; u2 < 2; ++u2)
                    acc[mt][u2] = __builtin_amdgcn_mfma_f32_16x16x32_f16(af[mt], bf[kk][u2], acc[mt][u2], 0, 0, 0);
        }
    };
    auto load_bfrag = [&](f16x8 bf[4][2], int h) {
        #pragma unroll
        for (int u2 = 0; u2 < 2; ++u2)
            #pragma unroll
            for (int kk = 0; kk < 4; ++kk) {
                const int s = 32 * h + 16 * u2 + lr;
                bf[kk][u2] = *(const f16x8*)(h3b + ((s * 256 + (32 * kk + 8 * g) * 2) ^ ((s & 7) << 4)));
            }
    };
    // inp-phase for half h, waves [0,nw)
    auto do_inp = [&](int h, int nw) {
        f16x8 bf[4][2];
        load_bfrag(bf, h);
        f16x4 xmr[4][2];
        #pragma unroll
        for (int mt = 0; mt < 4; ++mt)
            #pragma unroll
            for (int u2 = 0; u2 < 2; ++u2) {
                const f32x4 xv = *(const f32x4*)&xm_s[(32 * h + 16 * u2 + lr) * 68 + 16 * mt + 4 * g];
                f16x4 xh;
                #pragma unroll
                for (int q = 0; q < 4; ++q) xh[q] = (f16)xv[q];
                xmr[mt][u2] = xh;
            }
        for (int c = w; c < 65; c += nw) {
            f32x4 acc[4][2];
            gemm_chunk(c, bf, acc);
            f32x4 bv[4];
            #pragma unroll
            for (int mt = 0; mt < 4; ++mt)
                bv[mt] = *(const f32x4*)&b4[64 * c + 16 * mt + 4 * g];
            if (c < 64) {
                #pragma unroll
                for (int u2 = 0; u2 < 2; ++u2) {
                    float sum = 0.f;
                    #pragma unroll
                    for (int mt = 0; mt < 4; ++mt)
                        #pragma unroll
                        for (int q = 0; q < 4; ++q)
                            sum += (acc[mt][u2][q] + bv[mt][q]) * (float)xmr[mt][u2][q];
                    sum += __shfl_xor(sum, 16);
                    sum += __shfl_xor(sum, 32);
                    if (g == 0) hid_s[(32 * h + 16 * u2 + lr) * 68 + c] = sum;
                }
            } else {                         // inp_b tile for this half
                #pragma unroll
                for (int u2 = 0; u2 < 2; ++u2)
                    #pragma unroll
                    for (int mt = 0; mt < 4; ++mt) {
                        f16x4 wv;
                        #pragma unroll
                        for (int q = 0; q < 4; ++q)
                            wv[q] = (f16)(acc[mt][u2][q] + bv[mt][q]);
                        *(f16x4*)&w64_s[(32 * h + 16 * u2 + lr) * 64 + 16 * mt + 4 * g] = wv;
                    }
            }
        }
    };

    // ---- H0 inp-GEMM on waves 0-6; wave 7 drains H1 under it
    if (w < 7) {
        do_inp(0, 7);
    } else {
        #pragma unroll
        for (int k = 0; k < 32; ++k)         // vmcnt drain of own gathers
            xm_s[(32 + k) * 68 + lane] = xr[k];
    }
    BAR();                                   // B5a: H0 hid/w64 + xm_H1 ready

    // ---- H1 inp-GEMM on all 8 waves
    do_inp(1, 8);
    BAR();                                   // B5b: all hid/w64 done

    // ---- out-phase: waves 0-3 -> H0, waves 4-7 -> H1
    {
        const int h = (w >= 4), wid = w & 3;
        f16x8 bf[4][2];
        load_bfrag(bf, h);
        f16x4 hidr[4][2];
        #pragma unroll
        for (int mt = 0; mt < 4; ++mt)
            #pragma unroll
            for (int u2 = 0; u2 < 2; ++u2) {
                const int s = 32 * h + 16 * u2 + lr;
                f16x4 xh;
                #pragma unroll
                for (int q = 0; q < 4; ++q) {
                    const int hh = 16 * mt + 4 * g + q;
                    xh[q] = (f16)fmaxf(hid_s[s * 68 + hh] + (float)w64_s[s * 64 + hh], 0.f);
                }
                hidr[mt][u2] = xh;
            }
        for (int c = 65 + wid; c <= 75; c += 4) {
            if (c < 75) {
                f32x4 acc[4][2];
                gemm_chunk(c, bf, acc);
                f32x4 bv[4];
                #pragma unroll
                for (int mt = 0; mt < 4; ++mt)
                    bv[mt] = *(const f32x4*)&b4[64 * c + 16 * mt + 4 * g];
                #pragma unroll
                for (int u2 = 0; u2 < 2; ++u2) {
                    float sum = 0.f;
                    #pragma unroll
                    for (int mt = 0; mt < 4; ++mt)
                        #pragma unroll
                        for (int q = 0; q < 4; ++q)
                            sum += (acc[mt][u2][q] + bv[mt][q]) * (float)hidr[mt][u2][q];
                    sum += __shfl_xor(sum, 16);
                    sum += __shfl_xor(sum, 32);
                    if (g == 0) res_s[(32 * h + 16 * u2 + lr) * 12 + (c - 65)] = sum;
                }
            } else {                         // c == 75: out_b rows 4800..4809
                f32x4 accb[2] = {zero, zero};
                #pragma unroll
                for (int kk = 0; kk < 4; ++kk) {
                    const f16x8 af = *(const f16x8*)(W4b + (size_t)75 * 16384 + kk * 4096 + afoff);
                    #pragma unroll
                    for (int u2 = 0; u2 < 2; ++u2)
                        accb[u2] = __builtin_amdgcn_mfma_f32_16x16x32_f16(af, bf[kk][u2], accb[u2], 0, 0, 0);
                }
                #pragma unroll
                for (int u2 = 0; u2 < 2; ++u2)
                    #pragma unroll
                    for (int q = 0; q < 4; ++q) {
                        const int o = 4 * g + q;
                        if (o < 10)
                            res_b[(32 * h + 16 * u2 + lr) * 12 + o] = accb[u2][q] + b4[4800 + o];
                    }
            }
        }
    }
    BAR();                                   // B6: res ready

    for (int e = t; e < 640; e += 512)
        out[(size_t)row0 * 10 + e] =
            res_s[(e / 10) * 12 + (e % 10)] + res_b[(e / 10) * 12 + (e % 10)];
}

// ---------------------------------------------------------------- launcher
extern "C" void kernel_launch(void* const* d_in, const int* in_sizes, int n_in,
                              void* d_out, int out_size, void* d_ws, size_t ws_size,
                              hipStream_t stream)
{
    const float* data = (const float*)d_in[0];
    const int*   midx = (const int*)d_in[1];
    const float* W1   = (const float*)d_in[2];
    const float* b1   = (const float*)d_in[3];
    const float* W2   = (const float*)d_in[4];
    const float* b2   = (const float*)d_in[5];
    const float* W3   = (const float*)d_in[6];
    const float* b3   = (const float*)d_in[7];
    const float* W4   = (const float*)d_in[8];
    const float* b4   = (const float*)d_in[9];
    float* out = (float*)d_out;

    f16* W1Th = (f16*)d_ws;                    // 262144 f16
    f16* W4s  = W1Th + (size_t)4096 * 64;      // 622592 f16 (fragment-ordered)
    f16* W2h  = W4s + (size_t)NPAD * 128;      // 16384 f16
    f16* W3h  = W2h + 256 * 64;                // 32768 f16

    k_prep<<<512, 256, 0, stream>>>(W1, W2, W3, W4, W1Th, W2h, W3h, W4s);
    k_main<<<256, 512, 0, stream>>>(data, midx, W1Th, b1, W2h, b2, W3h, b3,
                                    W4s, b4, out);
}